// Round 1
// baseline (157.533 us; speedup 1.0000x reference)
//
#include <hip/hip_runtime.h>
#include <stdint.h>

// CoEncoderDynamicAttention: B=2,S=2048,H=1024,NH=16,NKV=4,HD=64, out=(B,S,1)
// out[b,q] = sum_h (sum_k e_{hqk} * vproj[b,h,k]) / (sum_k e_{hqk})
// vproj = hs @ (wv folded with wo)  -> attn@V GEMM eliminated.
// Q' = hs@wq * (log2e/8)  -> weight = exp2(Q'.K).
// Mask folded as accumulator-init bias (0 / -30000) -> exp2 gives exact 0.
// R1: gemm = double-buffered prefetch pipeline (1 barrier/iter);
//     attn = ks-loop inside block (Q/vproj/bias loaded once), atomicAdd -> out,
//     combine kernel eliminated.

typedef __bf16 bf16x8 __attribute__((ext_vector_type(8)));
typedef float f32x4 __attribute__((ext_vector_type(4)));

__device__ inline unsigned short f2bf(float f) {
    unsigned int u = __builtin_bit_cast(unsigned int, f);
    u += 0x7fff + ((u >> 16) & 1);   // RNE
    return (unsigned short)(u >> 16);
}
__device__ inline bf16x8 ldfrag(const unsigned short* p) {
    uint4 v = *(const uint4*)p;
    return __builtin_bit_cast(bf16x8, v);
}
__device__ inline void gl2lds16(const unsigned short* g, unsigned short* l) {
    // 64 lanes x 16B: per-lane global addr, LDS dst = wave-uniform base + lane*16
    __builtin_amdgcn_global_load_lds(
        (const __attribute__((address_space(1))) void*)g,
        (__attribute__((address_space(3))) void*)l, 16, 0, 0);
}

#define SCALE_Q 0.18033688011112042f   // log2(e)/8

// ---------------- prep: hs->bf16; wT = [wq^T*s | wk^T | wvo^T | zeros] (1408x1024 bf16)
// + zero out[] (4 blocks) for attn's atomicAdd
__global__ __launch_bounds__(256) void prep_kernel(
    const float* __restrict__ hs, const float* __restrict__ wq,
    const float* __restrict__ wk, const float* __restrict__ wv,
    const float* __restrict__ wo,
    unsigned short* __restrict__ hs_bf, unsigned short* __restrict__ wT,
    float* __restrict__ out)
{
    int bid = blockIdx.x, tid = threadIdx.x;
    if (bid < 4096) {
        int u = bid * 256 + tid;
        float4 v = ((const float4*)hs)[u];
        ushort4 o;
        o.x = f2bf(v.x); o.y = f2bf(v.y); o.z = f2bf(v.z); o.w = f2bf(v.w);
        ((ushort4*)hs_bf)[u] = o;
    } else if (bid < 4416) {
        __shared__ float tile[64 * 65];
        int t = bid - 4096;
        int ntile = t / 16, ctile = t % 16;
        int nb = ntile * 64, cb = ctile * 64;
        int tx = tid & 63, ty = tid >> 6;
        for (int i = 0; i < 16; i++) {
            int cl = i * 4 + ty;
            int n = nb + tx;
            float v = (n < 1024) ? wq[(cb + cl) * 1024 + n] * SCALE_Q
                                 : wk[(cb + cl) * 256 + (n - 1024)];
            tile[cl * 65 + tx] = v;
        }
        __syncthreads();
        for (int i = 0; i < 16; i++) {
            int nl = i * 4 + ty;
            wT[(nb + nl) * 1024 + cb + tx] = f2bf(tile[tx * 65 + nl]);
        }
    } else if (bid < 4928) {
        int u = (bid - 4416) * 256 + tid;
        int n2 = u >> 10, c = u & 1023;
        if (n2 < 16) {
            int h = n2, kv = h >> 2;
            const float* wvr = wv + c * 256 + kv * 64;
            const float* wor = wo + h * 64;
            float s = 0.f;
            #pragma unroll 8
            for (int d = 0; d < 64; d++) s += wvr[d] * wor[d];
            wT[(1280 + n2) * 1024 + c] = f2bf(s);
        } else {
            wT[(1280 + n2) * 1024 + c] = 0;
        }
    } else {
        // zero out: 4096 floats = 1024 float4, 4 blocks x 256 threads
        int u = (bid - 4928) * 256 + tid;
        float4 z = {0.f, 0.f, 0.f, 0.f};
        ((float4*)out)[u] = z;
    }
}

// ---------------- gemm (dbuf pipeline): D[n][r] = sum_c wT[n][c]*hs_bf[r][c]
// n-tiles: 0..7 -> Q' bf16, 8..9 -> K bf16, 10 -> vproj f32
__global__ __launch_bounds__(256) void gemm_kernel(
    const unsigned short* __restrict__ hs_bf, const unsigned short* __restrict__ wT,
    unsigned short* __restrict__ Qp, unsigned short* __restrict__ Kp,
    float* __restrict__ vproj)
{
    __shared__ __align__(16) unsigned short Al[2][128 * 32];  // unpadded: global_load_lds lane order
    __shared__ __align__(16) unsigned short Bl[2][128 * 32];
    int nt = blockIdx.x, rt = blockIdx.y;
    int tid = threadIdx.x;
    int lane = tid & 63, w = tid >> 6;
    int l15 = lane & 15, quad = lane >> 4;
    int wm = (w >> 1) * 64, wn = (w & 1) * 64;

    f32x4 acc[4][4];
    const f32x4 zero = {0.f, 0.f, 0.f, 0.f};
    for (int i = 0; i < 4; i++) for (int j = 0; j < 4; j++) acc[i][j] = zero;

    int arow = nt * 128, rrow = rt * 128;
    // staging: wave w covers rows w*32..w*32+31 in two 16-row chunks
    int srow = w * 32 + (lane >> 2);
    int scol = (lane & 3) * 8;
    const unsigned short* ga = wT    + (size_t)(arow + srow) * 1024 + scol;
    const unsigned short* gb = hs_bf + (size_t)(rrow + srow) * 1024 + scol;
    int lofs = (w * 32) * 32;

    // prologue: stage k-tile 0 into buf 0
    gl2lds16(ga,             Al[0] + lofs);
    gl2lds16(ga + 16 * 1024, Al[0] + lofs + 16 * 32);
    gl2lds16(gb,             Bl[0] + lofs);
    gl2lds16(gb + 16 * 1024, Bl[0] + lofs + 16 * 32);
    ga += 32; gb += 32;
    __syncthreads();

    for (int kk = 0; kk < 32; kk++) {
        int cur = kk & 1, nxt = cur ^ 1;
        if (kk < 31) {   // issue next-tile prefetch BEFORE compute; lands by the barrier
            gl2lds16(ga,             Al[nxt] + lofs);
            gl2lds16(ga + 16 * 1024, Al[nxt] + lofs + 16 * 32);
            gl2lds16(gb,             Bl[nxt] + lofs);
            gl2lds16(gb + 16 * 1024, Bl[nxt] + lofs + 16 * 32);
            ga += 32; gb += 32;
        }
        bf16x8 af[4], bfr[4];
        for (int i = 0; i < 4; i++) {
            af[i]  = ldfrag(Al[cur] + (wm + i * 16 + l15) * 32 + quad * 8);
            bfr[i] = ldfrag(Bl[cur] + (wn + i * 16 + l15) * 32 + quad * 8);
        }
        for (int i = 0; i < 4; i++)
            for (int j = 0; j < 4; j++)
                acc[i][j] = __builtin_amdgcn_mfma_f32_16x16x32_bf16(af[i], bfr[j], acc[i][j], 0, 0, 0);
        __syncthreads();   // drains prefetch vmcnt + everyone done reading buf[cur]
    }

    for (int i = 0; i < 4; i++) {
        for (int j = 0; j < 4; j++) {
            int nw = nt * 128 + wm + i * 16 + quad * 4;
            int r  = rt * 128 + wn + j * 16 + l15;
            if (nt < 8) {
                ushort4 o;
                o.x = f2bf(acc[i][j][0]); o.y = f2bf(acc[i][j][1]);
                o.z = f2bf(acc[i][j][2]); o.w = f2bf(acc[i][j][3]);
                *(ushort4*)(Qp + (size_t)r * 1024 + nw) = o;
            } else if (nt < 10) {
                ushort4 o;
                o.x = f2bf(acc[i][j][0]); o.y = f2bf(acc[i][j][1]);
                o.z = f2bf(acc[i][j][2]); o.w = f2bf(acc[i][j][3]);
                *(ushort4*)(Kp + (size_t)r * 256 + (nw - 1024)) = o;
            } else {
                for (int rg = 0; rg < 4; rg++) {
                    int h = nw + rg - 1280;
                    if (h < 16)
                        vproj[((size_t)(r >> 11) * 16 + h) * 2048 + (r & 2047)] = acc[i][j][rg];
                }
            }
        }
    }
}

// ---------------- attention v3: block = (qt 0..63 [32 q-rows], b*4+kv); wave w -> h = kv*4+w.
// ks loop INSIDE the block: Q frags + vproj slice + bias staged ONCE, K tile per chunk.
// Block produces complete num/den -> divide -> reduce 4 heads -> atomicAdd to out.
// LDS = 40960 (Kl) + 32768 (vpml) + 8192 (biasl) = 80 KB -> 2 blocks/CU.
__global__ __launch_bounds__(256) void attn_kernel(
    const unsigned short* __restrict__ Qp, const unsigned short* __restrict__ Kp,
    const float* __restrict__ vproj, const int* __restrict__ mask,
    float* __restrict__ out)
{
    __shared__ __align__(16) unsigned short Kl[256 * 80];  // stride 80: measured 0 conflicts
    __shared__ __align__(16) float vpml[4 * 2048];
    __shared__ __align__(16) float biasl[2048];
    int qt = blockIdx.x;                       // 0..63 -> 32 q rows each
    int b = blockIdx.y >> 2, kv = blockIdx.y & 3;
    int tid = threadIdx.x, lane = tid & 63, w = tid >> 6;
    int l15 = lane & 15, quad = lane >> 4;
    int h = kv * 4 + w;
    int qrow0 = qt * 32;

    // Q fragments once: B-operand layout B[n=q (l15)][k=d (quad*8..)]
    bf16x8 qf[2][2];
    for (int qs = 0; qs < 2; qs++) {
        const unsigned short* qp =
            Qp + (size_t)(b * 2048 + qrow0 + qs * 16 + l15) * 1024 + h * 64 + quad * 8;
        qf[qs][0] = ldfrag(qp);
        qf[qs][1] = ldfrag(qp + 32);
    }

    // stage full vproj slice (4 h x 2048 k f32): 8192 floats = 2048 float4
    for (int it = 0; it < 8; it++) {
        int u = it * 256 + tid;
        int h2 = u >> 9, kk = (u & 511) * 4;
        *(float4*)(vpml + h2 * 2048 + kk) =
            *(const float4*)(vproj + ((size_t)b * 16 + kv * 4 + h2) * 2048 + kk);
    }
    // stage full bias (2048 entries)
    for (int it = 0; it < 2; it++) {
        int idx = (it * 256 + tid) * 4;
        int4 mm = *(const int4*)(mask + b * 2048 + idx);
        float4 bb;
        bb.x = mm.x ? 0.f : -30000.f;
        bb.y = mm.y ? 0.f : -30000.f;
        bb.z = mm.z ? 0.f : -30000.f;
        bb.w = mm.w ? 0.f : -30000.f;
        *(float4*)(biasl + idx) = bb;
    }

    float num[2] = {0.f, 0.f}, den[2] = {0.f, 0.f};
    for (int ks = 0; ks < 8; ks++) {
        __syncthreads();   // previous chunk's compute done reading Kl (iter 0: no-op)
        // stage K chunk (256 rows x 64 d): 2048 units of 8 shorts
        for (int it = 0; it < 8; it++) {
            int u = it * 256 + tid;
            int row = u >> 3, ch = u & 7;
            *(uint4*)(Kl + row * 80 + ch * 8) =
                *(const uint4*)(Kp + (size_t)(b * 2048 + ks * 256 + row) * 256 + kv * 64 + ch * 8);
        }
        __syncthreads();   // Kl ready (also orders vpml/biasl on iter 0)

        for (int t8 = 0; t8 < 16; t8++) {
            const unsigned short* kb = Kl + (t8 * 16 + l15) * 80 + quad * 8;
            bf16x8 a0 = ldfrag(kb);           // A[m=k-row (l15)][k=d 0..31]
            bf16x8 a1 = ldfrag(kb + 32);      // d 32..63
            f32x4 vpm4 = *(const f32x4*)(vpml + w * 2048 + ks * 256 + t8 * 16 + quad * 4);
            f32x4 c4   = *(const f32x4*)(biasl + ks * 256 + t8 * 16 + quad * 4);  // mask bias per k-row
            for (int qs = 0; qs < 2; qs++) {
                f32x4 d = __builtin_amdgcn_mfma_f32_16x16x32_bf16(a0, qf[qs][0], c4, 0, 0, 0);
                d = __builtin_amdgcn_mfma_f32_16x16x32_bf16(a1, qf[qs][1], d, 0, 0, 0);
                for (int r = 0; r < 4; r++) {
                    float e = __builtin_amdgcn_exp2f(d[r]);   // 0 for masked rows
                    num[qs] += e * vpm4[r];
                    den[qs] += e;
                }
            }
        }
    }

    // reduce over quad (k-row groups), divide, then reduce 4 heads via LDS, atomicAdd
    __syncthreads();                 // all compute done -> safe to alias Kl
    float* vsum = (float*)Kl;        // [4 waves][32 q]
    for (int qs = 0; qs < 2; qs++) {
        float n = num[qs], dd = den[qs];
        n += __shfl_xor(n, 16);  n += __shfl_xor(n, 32);
        dd += __shfl_xor(dd, 16); dd += __shfl_xor(dd, 32);
        if (quad == 0) vsum[w * 32 + qs * 16 + l15] = n / dd;
    }
    __syncthreads();
    if (tid < 32) {
        float v = vsum[tid] + vsum[32 + tid] + vsum[64 + tid] + vsum[96 + tid];
        atomicAdd(out + b * 2048 + qrow0 + tid, v);
    }
}

extern "C" void kernel_launch(void* const* d_in, const int* in_sizes, int n_in,
                              void* d_out, int out_size, void* d_ws, size_t ws_size,
                              hipStream_t stream)
{
    const float* hs  = (const float*)d_in[0];
    const int* mask  = (const int*)d_in[1];
    const float* wq  = (const float*)d_in[2];
    const float* wk  = (const float*)d_in[3];
    const float* wv  = (const float*)d_in[4];
    const float* wo  = (const float*)d_in[5];

    char* ws = (char*)d_ws;
    unsigned short* hs_bf = (unsigned short*)ws;               // 8,388,608 B
    unsigned short* wT    = (unsigned short*)(ws + 8388608);   // 2,883,584 B
    unsigned short* Qp    = (unsigned short*)(ws + 11272192);  // 8,388,608 B
    unsigned short* Kp    = (unsigned short*)(ws + 19660800);  // 2,097,152 B
    float* vproj          = (float*)(ws + 21757952);           //   262,144 B

    prep_kernel<<<4932, 256, 0, stream>>>(hs, wq, wk, wv, wo, hs_bf, wT, (float*)d_out);
    gemm_kernel<<<dim3(11, 32), 256, 0, stream>>>(hs_bf, wT, Qp, Kp, vproj);
    attn_kernel<<<dim3(64, 8), 256, 0, stream>>>(Qp, Kp, vproj, mask, (float*)d_out);
}

// Round 2
// 149.582 us; speedup vs baseline: 1.0532x; 1.0532x over previous
//
#include <hip/hip_runtime.h>
#include <stdint.h>

// CoEncoderDynamicAttention: B=2,S=2048,H=1024,NH=16,NKV=4,HD=64, out=(B,S,1)
// out[b,q] = sum_h (sum_k e_{hqk} * vproj[b,h,k]) / (sum_k e_{hqk})
// vproj = hs @ (wv folded with wo)  -> attn@V GEMM eliminated.
// Q' = hs@wq * (log2e/8)  -> weight = exp2(Q'.K).
// Mask folded as accumulator-init bias (0 / -30000) -> exp2 gives exact 0.
// R1: gemm = double-buffered prefetch pipeline (1 barrier/iter)  [kept: WIN]
// R2: attn reverted to R0 structure (2048 blocks, 4 q-chains/wave = latency-hiding
//     that R1's 512-block version destroyed; MfmaUtil was 12.5%) + s_setprio(1)
//     around MFMA pairs (T5); combine kernel restored.

typedef __bf16 bf16x8 __attribute__((ext_vector_type(8)));
typedef float f32x4 __attribute__((ext_vector_type(4)));

__device__ inline unsigned short f2bf(float f) {
    unsigned int u = __builtin_bit_cast(unsigned int, f);
    u += 0x7fff + ((u >> 16) & 1);   // RNE
    return (unsigned short)(u >> 16);
}
__device__ inline bf16x8 ldfrag(const unsigned short* p) {
    uint4 v = *(const uint4*)p;
    return __builtin_bit_cast(bf16x8, v);
}
__device__ inline void gl2lds16(const unsigned short* g, unsigned short* l) {
    // 64 lanes x 16B: per-lane global addr, LDS dst = wave-uniform base + lane*16
    __builtin_amdgcn_global_load_lds(
        (const __attribute__((address_space(1))) void*)g,
        (__attribute__((address_space(3))) void*)l, 16, 0, 0);
}

#define SCALE_Q 0.18033688011112042f   // log2(e)/8

// ---------------- prep: hs->bf16; wT = [wq^T*s | wk^T | wvo^T | zeros] (1408x1024 bf16)
__global__ __launch_bounds__(256) void prep_kernel(
    const float* __restrict__ hs, const float* __restrict__ wq,
    const float* __restrict__ wk, const float* __restrict__ wv,
    const float* __restrict__ wo,
    unsigned short* __restrict__ hs_bf, unsigned short* __restrict__ wT)
{
    int bid = blockIdx.x, tid = threadIdx.x;
    if (bid < 4096) {
        int u = bid * 256 + tid;
        float4 v = ((const float4*)hs)[u];
        ushort4 o;
        o.x = f2bf(v.x); o.y = f2bf(v.y); o.z = f2bf(v.z); o.w = f2bf(v.w);
        ((ushort4*)hs_bf)[u] = o;
    } else if (bid < 4416) {
        __shared__ float tile[64 * 65];
        int t = bid - 4096;
        int ntile = t / 16, ctile = t % 16;
        int nb = ntile * 64, cb = ctile * 64;
        int tx = tid & 63, ty = tid >> 6;
        for (int i = 0; i < 16; i++) {
            int cl = i * 4 + ty;
            int n = nb + tx;
            float v = (n < 1024) ? wq[(cb + cl) * 1024 + n] * SCALE_Q
                                 : wk[(cb + cl) * 256 + (n - 1024)];
            tile[cl * 65 + tx] = v;
        }
        __syncthreads();
        for (int i = 0; i < 16; i++) {
            int nl = i * 4 + ty;
            wT[(nb + nl) * 1024 + cb + tx] = f2bf(tile[tx * 65 + nl]);
        }
    } else {
        int u = (bid - 4416) * 256 + tid;
        int n2 = u >> 10, c = u & 1023;
        if (n2 < 16) {
            int h = n2, kv = h >> 2;
            const float* wvr = wv + c * 256 + kv * 64;
            const float* wor = wo + h * 64;
            float s = 0.f;
            #pragma unroll 8
            for (int d = 0; d < 64; d++) s += wvr[d] * wor[d];
            wT[(1280 + n2) * 1024 + c] = f2bf(s);
        } else {
            wT[(1280 + n2) * 1024 + c] = 0;
        }
    }
}

// ---------------- gemm (dbuf pipeline): D[n][r] = sum_c wT[n][c]*hs_bf[r][c]
// n-tiles: 0..7 -> Q' bf16, 8..9 -> K bf16, 10 -> vproj f32
__global__ __launch_bounds__(256) void gemm_kernel(
    const unsigned short* __restrict__ hs_bf, const unsigned short* __restrict__ wT,
    unsigned short* __restrict__ Qp, unsigned short* __restrict__ Kp,
    float* __restrict__ vproj)
{
    __shared__ __align__(16) unsigned short Al[2][128 * 32];  // unpadded: global_load_lds lane order
    __shared__ __align__(16) unsigned short Bl[2][128 * 32];
    int nt = blockIdx.x, rt = blockIdx.y;
    int tid = threadIdx.x;
    int lane = tid & 63, w = tid >> 6;
    int l15 = lane & 15, quad = lane >> 4;
    int wm = (w >> 1) * 64, wn = (w & 1) * 64;

    f32x4 acc[4][4];
    const f32x4 zero = {0.f, 0.f, 0.f, 0.f};
    for (int i = 0; i < 4; i++) for (int j = 0; j < 4; j++) acc[i][j] = zero;

    int arow = nt * 128, rrow = rt * 128;
    // staging: wave w covers rows w*32..w*32+31 in two 16-row chunks
    int srow = w * 32 + (lane >> 2);
    int scol = (lane & 3) * 8;
    const unsigned short* ga = wT    + (size_t)(arow + srow) * 1024 + scol;
    const unsigned short* gb = hs_bf + (size_t)(rrow + srow) * 1024 + scol;
    int lofs = (w * 32) * 32;

    // prologue: stage k-tile 0 into buf 0
    gl2lds16(ga,             Al[0] + lofs);
    gl2lds16(ga + 16 * 1024, Al[0] + lofs + 16 * 32);
    gl2lds16(gb,             Bl[0] + lofs);
    gl2lds16(gb + 16 * 1024, Bl[0] + lofs + 16 * 32);
    ga += 32; gb += 32;
    __syncthreads();

    for (int kk = 0; kk < 32; kk++) {
        int cur = kk & 1, nxt = cur ^ 1;
        if (kk < 31) {   // issue next-tile prefetch BEFORE compute; lands by the barrier
            gl2lds16(ga,             Al[nxt] + lofs);
            gl2lds16(ga + 16 * 1024, Al[nxt] + lofs + 16 * 32);
            gl2lds16(gb,             Bl[nxt] + lofs);
            gl2lds16(gb + 16 * 1024, Bl[nxt] + lofs + 16 * 32);
            ga += 32; gb += 32;
        }
        bf16x8 af[4], bfr[4];
        for (int i = 0; i < 4; i++) {
            af[i]  = ldfrag(Al[cur] + (wm + i * 16 + l15) * 32 + quad * 8);
            bfr[i] = ldfrag(Bl[cur] + (wn + i * 16 + l15) * 32 + quad * 8);
        }
        for (int i = 0; i < 4; i++)
            for (int j = 0; j < 4; j++)
                acc[i][j] = __builtin_amdgcn_mfma_f32_16x16x32_bf16(af[i], bfr[j], acc[i][j], 0, 0, 0);
        __syncthreads();   // drains prefetch vmcnt + everyone done reading buf[cur]
    }

    for (int i = 0; i < 4; i++) {
        for (int j = 0; j < 4; j++) {
            int nw = nt * 128 + wm + i * 16 + quad * 4;
            int r  = rt * 128 + wn + j * 16 + l15;
            if (nt < 8) {
                ushort4 o;
                o.x = f2bf(acc[i][j][0]); o.y = f2bf(acc[i][j][1]);
                o.z = f2bf(acc[i][j][2]); o.w = f2bf(acc[i][j][3]);
                *(ushort4*)(Qp + (size_t)r * 1024 + nw) = o;
            } else if (nt < 10) {
                ushort4 o;
                o.x = f2bf(acc[i][j][0]); o.y = f2bf(acc[i][j][1]);
                o.z = f2bf(acc[i][j][2]); o.w = f2bf(acc[i][j][3]);
                *(ushort4*)(Kp + (size_t)r * 256 + (nw - 1024)) = o;
            } else {
                for (int rg = 0; rg < 4; rg++) {
                    int h = nw + rg - 1280;
                    if (h < 16)
                        vproj[((size_t)(r >> 11) * 16 + h) * 2048 + (r & 2047)] = acc[i][j][rg];
                }
            }
        }
    }
}

// ---------------- attention (R0 structure): block = (b,kv,qtile64,ks256); wave w -> h = kv*4+w.
// One shared K tile (256x64) staged once; 4 independent q-chains per wave;
// mask enters as MFMA accumulator-init bias. setprio(1) around MFMA pairs (T5).
__global__ __launch_bounds__(256) void attn_kernel(
    const unsigned short* __restrict__ Qp, const unsigned short* __restrict__ Kp,
    const float* __restrict__ vproj, const int* __restrict__ mask,
    float2* __restrict__ part)
{
    __shared__ __align__(16) unsigned short Kl[256 * 80];  // stride 80: measured 0 conflicts
    __shared__ __align__(16) float vpml[4 * 256];
    __shared__ __align__(16) float biasl[256];
    int qt = blockIdx.x;                       // 0..31
    int b = blockIdx.y >> 2, kv = blockIdx.y & 3;
    int ks = blockIdx.z;                       // 0..7
    int tid = threadIdx.x, lane = tid & 63, w = tid >> 6;
    int l15 = lane & 15, quad = lane >> 4;
    int h = kv * 4 + w;
    int k0 = ks * 256;
    int qrow0 = qt * 64;

    // Q fragments: B-operand layout B[n=q (l15)][k=d (quad*8..)]
    bf16x8 qf[4][2];
    for (int qs = 0; qs < 4; qs++) {
        const unsigned short* qp =
            Qp + (size_t)(b * 2048 + qrow0 + qs * 16 + l15) * 1024 + h * 64 + quad * 8;
        qf[qs][0] = ldfrag(qp);
        qf[qs][1] = ldfrag(qp + 32);
    }

    // stage K (256 rows x 64 d): 256 rows x 8 chunks of 8 shorts = 2048 units
    for (int it = 0; it < 8; it++) {
        int u = it * 256 + tid;
        int row = u >> 3, ch = u & 7;
        *(uint4*)(Kl + row * 80 + ch * 8) =
            *(const uint4*)(Kp + (size_t)(b * 2048 + k0 + row) * 256 + kv * 64 + ch * 8);
    }
    {   // vproj slice per h (4 h x 256 k)
        int h2 = tid >> 6, kk = (tid & 63) * 4;
        *(float4*)(vpml + h2 * 256 + kk) =
            *(const float4*)(vproj + ((size_t)b * 16 + kv * 4 + h2) * 2048 + k0 + kk);
    }
    if (tid < 64) {
        int4 mm = *(const int4*)(mask + b * 2048 + k0 + tid * 4);
        float4 bb;
        bb.x = mm.x ? 0.f : -30000.f;
        bb.y = mm.y ? 0.f : -30000.f;
        bb.z = mm.z ? 0.f : -30000.f;
        bb.w = mm.w ? 0.f : -30000.f;
        *(float4*)(biasl + tid * 4) = bb;
    }
    __syncthreads();

    float num[4] = {0.f, 0.f, 0.f, 0.f}, den[4] = {0.f, 0.f, 0.f, 0.f};
    for (int t8 = 0; t8 < 16; t8++) {
        const unsigned short* kb = Kl + (t8 * 16 + l15) * 80 + quad * 8;
        bf16x8 a0 = ldfrag(kb);           // A[m=k-row (l15)][k=d 0..31]
        bf16x8 a1 = ldfrag(kb + 32);      // d 32..63
        f32x4 vpm4 = *(const f32x4*)(vpml + w * 256 + t8 * 16 + quad * 4);
        f32x4 c4   = *(const f32x4*)(biasl + t8 * 16 + quad * 4);  // mask bias per k-row
        for (int qs = 0; qs < 4; qs++) {
            __builtin_amdgcn_s_setprio(1);
            f32x4 d = __builtin_amdgcn_mfma_f32_16x16x32_bf16(a0, qf[qs][0], c4, 0, 0, 0);
            d = __builtin_amdgcn_mfma_f32_16x16x32_bf16(a1, qf[qs][1], d, 0, 0, 0);
            __builtin_amdgcn_s_setprio(0);
            for (int r = 0; r < 4; r++) {
                float e = __builtin_amdgcn_exp2f(d[r]);   // 0 for masked rows
                num[qs] += e * vpm4[r];
                den[qs] += e;
            }
        }
    }
    for (int qs = 0; qs < 4; qs++) {
        float n = num[qs], dd = den[qs];
        n += __shfl_xor(n, 16);  n += __shfl_xor(n, 32);
        dd += __shfl_xor(dd, 16); dd += __shfl_xor(dd, 32);
        if (quad == 0) {
            int q = qrow0 + qs * 16 + l15;
            part[((size_t)(b * 2048 + q) * 16 + h) * 8 + ks] = make_float2(n, dd);
        }
    }
}

// ---------------- combine: out[b,q] = sum_h (sum_ks num)/(sum_ks den)
__global__ __launch_bounds__(256) void combine_kernel(
    const float2* __restrict__ part, float* __restrict__ out)
{
    int wid = (blockIdx.x * 256 + threadIdx.x) >> 6;  // (b,q)
    int lane = threadIdx.x & 63;
    const float2* base = part + (size_t)wid * 128;    // 16 h x 8 ks
    float2 p0 = base[lane];
    float2 p1 = base[64 + lane];
    for (int m = 1; m <= 4; m <<= 1) {
        p0.x += __shfl_xor(p0.x, m); p0.y += __shfl_xor(p0.y, m);
        p1.x += __shfl_xor(p1.x, m); p1.y += __shfl_xor(p1.y, m);
    }
    float v = p0.x / p0.y + p1.x / p1.y;
    for (int m = 8; m <= 32; m <<= 1) v += __shfl_xor(v, m);  // 8 distinct h-groups, once each
    if (lane == 0) out[wid] = v;
}

extern "C" void kernel_launch(void* const* d_in, const int* in_sizes, int n_in,
                              void* d_out, int out_size, void* d_ws, size_t ws_size,
                              hipStream_t stream)
{
    const float* hs  = (const float*)d_in[0];
    const int* mask  = (const int*)d_in[1];
    const float* wq  = (const float*)d_in[2];
    const float* wk  = (const float*)d_in[3];
    const float* wv  = (const float*)d_in[4];
    const float* wo  = (const float*)d_in[5];

    char* ws = (char*)d_ws;
    unsigned short* hs_bf = (unsigned short*)ws;               // 8,388,608 B
    unsigned short* wT    = (unsigned short*)(ws + 8388608);   // 2,883,584 B
    unsigned short* Qp    = (unsigned short*)(ws + 11272192);  // 8,388,608 B
    unsigned short* Kp    = (unsigned short*)(ws + 19660800);  // 2,097,152 B
    float* vproj          = (float*)(ws + 21757952);           //   262,144 B
    float2* part          = (float2*)(ws + 22020096);          // 4,194,304 B

    prep_kernel<<<4928, 256, 0, stream>>>(hs, wq, wk, wv, wo, hs_bf, wT);
    gemm_kernel<<<dim3(11, 32), 256, 0, stream>>>(hs_bf, wT, Qp, Kp, vproj);
    attn_kernel<<<dim3(32, 8, 8), 256, 0, stream>>>(Qp, Kp, vproj, mask, part);
    combine_kernel<<<1024, 256, 0, stream>>>(part, (float*)d_out);
}

// Round 3
// 143.232 us; speedup vs baseline: 1.0998x; 1.0443x over previous
//
#include <hip/hip_runtime.h>
#include <stdint.h>

// CoEncoderDynamicAttention: B=2,S=2048,H=1024,NH=16,NKV=4,HD=64, out=(B,S,1)
// out[b,q] = sum_h (sum_k e_{hqk} * vproj[b,h,k]) / (sum_k e_{hqk})
// vproj = hs @ (wv folded with wo)  -> attn@V GEMM eliminated.
// Q' = hs@wq * (log2e/8)  -> weight = exp2(Q'.K).
// Mask folded as accumulator-init bias (0 / -30000) -> exp2 gives exact 0.
// R1: gemm = double-buffered prefetch pipeline (1 barrier/iter)  [kept]
// R2: attn = R0 structure (2048 blocks, 4 q-chains/wave) + setprio  [kept]
// R3: gemm XCD-aware block remap (T1): 44 blocks/XCD = 4 rt-groups x 11 nt ->
//     each 256KB B-tile fetched into ONE XCD's L2 instead of 8 (B L3 traffic
//     67MB -> 8.4MB). attn: packed f32x2 accumulate (v_pk_fma_f32) halves
//     the num/den VALU ops.

typedef __bf16 bf16x8 __attribute__((ext_vector_type(8)));
typedef float f32x4 __attribute__((ext_vector_type(4)));
typedef float f32x2 __attribute__((ext_vector_type(2)));

__device__ inline unsigned short f2bf(float f) {
    unsigned int u = __builtin_bit_cast(unsigned int, f);
    u += 0x7fff + ((u >> 16) & 1);   // RNE
    return (unsigned short)(u >> 16);
}
__device__ inline bf16x8 ldfrag(const unsigned short* p) {
    uint4 v = *(const uint4*)p;
    return __builtin_bit_cast(bf16x8, v);
}
__device__ inline void gl2lds16(const unsigned short* g, unsigned short* l) {
    // 64 lanes x 16B: per-lane global addr, LDS dst = wave-uniform base + lane*16
    __builtin_amdgcn_global_load_lds(
        (const __attribute__((address_space(1))) void*)g,
        (__attribute__((address_space(3))) void*)l, 16, 0, 0);
}

#define SCALE_Q 0.18033688011112042f   // log2(e)/8

// ---------------- prep: hs->bf16; wT = [wq^T*s | wk^T | wvo^T | zeros] (1408x1024 bf16)
__global__ __launch_bounds__(256) void prep_kernel(
    const float* __restrict__ hs, const float* __restrict__ wq,
    const float* __restrict__ wk, const float* __restrict__ wv,
    const float* __restrict__ wo,
    unsigned short* __restrict__ hs_bf, unsigned short* __restrict__ wT)
{
    int bid = blockIdx.x, tid = threadIdx.x;
    if (bid < 4096) {
        int u = bid * 256 + tid;
        float4 v = ((const float4*)hs)[u];
        ushort4 o;
        o.x = f2bf(v.x); o.y = f2bf(v.y); o.z = f2bf(v.z); o.w = f2bf(v.w);
        ((ushort4*)hs_bf)[u] = o;
    } else if (bid < 4416) {
        __shared__ float tile[64 * 65];
        int t = bid - 4096;
        int ntile = t / 16, ctile = t % 16;
        int nb = ntile * 64, cb = ctile * 64;
        int tx = tid & 63, ty = tid >> 6;
        for (int i = 0; i < 16; i++) {
            int cl = i * 4 + ty;
            int n = nb + tx;
            float v = (n < 1024) ? wq[(cb + cl) * 1024 + n] * SCALE_Q
                                 : wk[(cb + cl) * 256 + (n - 1024)];
            tile[cl * 65 + tx] = v;
        }
        __syncthreads();
        for (int i = 0; i < 16; i++) {
            int nl = i * 4 + ty;
            wT[(nb + nl) * 1024 + cb + tx] = f2bf(tile[tx * 65 + nl]);
        }
    } else {
        int u = (bid - 4416) * 256 + tid;
        int n2 = u >> 10, c = u & 1023;
        if (n2 < 16) {
            int h = n2, kv = h >> 2;
            const float* wvr = wv + c * 256 + kv * 64;
            const float* wor = wo + h * 64;
            float s = 0.f;
            #pragma unroll 8
            for (int d = 0; d < 64; d++) s += wvr[d] * wor[d];
            wT[(1280 + n2) * 1024 + c] = f2bf(s);
        } else {
            wT[(1280 + n2) * 1024 + c] = 0;
        }
    }
}

// ---------------- gemm (dbuf pipeline + XCD remap): D[n][r] = sum_c wT[n][c]*hs_bf[r][c]
// n-tiles: 0..7 -> Q' bf16, 8..9 -> K bf16, 10 -> vproj f32
__global__ __launch_bounds__(256) void gemm_kernel(
    const unsigned short* __restrict__ hs_bf, const unsigned short* __restrict__ wT,
    unsigned short* __restrict__ Qp, unsigned short* __restrict__ Kp,
    float* __restrict__ vproj)
{
    __shared__ __align__(16) unsigned short Al[2][128 * 32];  // unpadded: global_load_lds lane order
    __shared__ __align__(16) unsigned short Bl[2][128 * 32];
    // XCD-aware remap: physical flat p -> XCD p%8 (round-robin dispatch).
    // Give XCD x the 4 rt-groups x*4..x*4+3 (44 blocks = 4x11), so the 11
    // same-rt blocks (sharing one 256KB B tile) all sit on one XCD's L2.
    int p = blockIdx.x + 11 * blockIdx.y;   // 0..351
    int xcd = p & 7;
    int j = p >> 3;                          // 0..43
    int rt = (xcd << 2) + j / 11;
    int nt = j % 11;
    int tid = threadIdx.x;
    int lane = tid & 63, w = tid >> 6;
    int l15 = lane & 15, quad = lane >> 4;
    int wm = (w >> 1) * 64, wn = (w & 1) * 64;

    f32x4 acc[4][4];
    const f32x4 zero = {0.f, 0.f, 0.f, 0.f};
    for (int i = 0; i < 4; i++) for (int j2 = 0; j2 < 4; j2++) acc[i][j2] = zero;

    int arow = nt * 128, rrow = rt * 128;
    // staging: wave w covers rows w*32..w*32+31 in two 16-row chunks
    int srow = w * 32 + (lane >> 2);
    int scol = (lane & 3) * 8;
    const unsigned short* ga = wT    + (size_t)(arow + srow) * 1024 + scol;
    const unsigned short* gb = hs_bf + (size_t)(rrow + srow) * 1024 + scol;
    int lofs = (w * 32) * 32;

    // prologue: stage k-tile 0 into buf 0
    gl2lds16(ga,             Al[0] + lofs);
    gl2lds16(ga + 16 * 1024, Al[0] + lofs + 16 * 32);
    gl2lds16(gb,             Bl[0] + lofs);
    gl2lds16(gb + 16 * 1024, Bl[0] + lofs + 16 * 32);
    ga += 32; gb += 32;
    __syncthreads();

    for (int kk = 0; kk < 32; kk++) {
        int cur = kk & 1, nxt = cur ^ 1;
        if (kk < 31) {   // issue next-tile prefetch BEFORE compute; lands by the barrier
            gl2lds16(ga,             Al[nxt] + lofs);
            gl2lds16(ga + 16 * 1024, Al[nxt] + lofs + 16 * 32);
            gl2lds16(gb,             Bl[nxt] + lofs);
            gl2lds16(gb + 16 * 1024, Bl[nxt] + lofs + 16 * 32);
            ga += 32; gb += 32;
        }
        bf16x8 af[4], bfr[4];
        for (int i = 0; i < 4; i++) {
            af[i]  = ldfrag(Al[cur] + (wm + i * 16 + l15) * 32 + quad * 8);
            bfr[i] = ldfrag(Bl[cur] + (wn + i * 16 + l15) * 32 + quad * 8);
        }
        for (int i = 0; i < 4; i++)
            for (int j2 = 0; j2 < 4; j2++)
                acc[i][j2] = __builtin_amdgcn_mfma_f32_16x16x32_bf16(af[i], bfr[j2], acc[i][j2], 0, 0, 0);
        __syncthreads();   // drains prefetch vmcnt + everyone done reading buf[cur]
    }

    for (int i = 0; i < 4; i++) {
        for (int j2 = 0; j2 < 4; j2++) {
            int nw = nt * 128 + wm + i * 16 + quad * 4;
            int r  = rt * 128 + wn + j2 * 16 + l15;
            if (nt < 8) {
                ushort4 o;
                o.x = f2bf(acc[i][j2][0]); o.y = f2bf(acc[i][j2][1]);
                o.z = f2bf(acc[i][j2][2]); o.w = f2bf(acc[i][j2][3]);
                *(ushort4*)(Qp + (size_t)r * 1024 + nw) = o;
            } else if (nt < 10) {
                ushort4 o;
                o.x = f2bf(acc[i][j2][0]); o.y = f2bf(acc[i][j2][1]);
                o.z = f2bf(acc[i][j2][2]); o.w = f2bf(acc[i][j2][3]);
                *(ushort4*)(Kp + (size_t)r * 256 + (nw - 1024)) = o;
            } else {
                for (int rg = 0; rg < 4; rg++) {
                    int h = nw + rg - 1280;
                    if (h < 16)
                        vproj[((size_t)(r >> 11) * 16 + h) * 2048 + (r & 2047)] = acc[i][j2][rg];
                }
            }
        }
    }
}

// ---------------- attention: block = (b,kv,qtile64,ks256); wave w -> h = kv*4+w.
// One shared K tile (256x64) staged once; 4 independent q-chains per wave;
// mask enters as MFMA accumulator-init bias. setprio(1) around MFMA pairs (T5).
// Accumulate (num,den) as packed f32x2 -> v_pk_fma_f32.
__global__ __launch_bounds__(256) void attn_kernel(
    const unsigned short* __restrict__ Qp, const unsigned short* __restrict__ Kp,
    const float* __restrict__ vproj, const int* __restrict__ mask,
    float2* __restrict__ part)
{
    __shared__ __align__(16) unsigned short Kl[256 * 80];  // stride 80: measured 0 conflicts
    __shared__ __align__(16) float vpml[4 * 256];
    __shared__ __align__(16) float biasl[256];
    int qt = blockIdx.x;                       // 0..31
    int b = blockIdx.y >> 2, kv = blockIdx.y & 3;
    int ks = blockIdx.z;                       // 0..7
    int tid = threadIdx.x, lane = tid & 63, w = tid >> 6;
    int l15 = lane & 15, quad = lane >> 4;
    int h = kv * 4 + w;
    int k0 = ks * 256;
    int qrow0 = qt * 64;

    // Q fragments: B-operand layout B[n=q (l15)][k=d (quad*8..)]
    bf16x8 qf[4][2];
    for (int qs = 0; qs < 4; qs++) {
        const unsigned short* qp =
            Qp + (size_t)(b * 2048 + qrow0 + qs * 16 + l15) * 1024 + h * 64 + quad * 8;
        qf[qs][0] = ldfrag(qp);
        qf[qs][1] = ldfrag(qp + 32);
    }

    // stage K (256 rows x 64 d): 256 rows x 8 chunks of 8 shorts = 2048 units
    for (int it = 0; it < 8; it++) {
        int u = it * 256 + tid;
        int row = u >> 3, ch = u & 7;
        *(uint4*)(Kl + row * 80 + ch * 8) =
            *(const uint4*)(Kp + (size_t)(b * 2048 + k0 + row) * 256 + kv * 64 + ch * 8);
    }
    {   // vproj slice per h (4 h x 256 k)
        int h2 = tid >> 6, kk = (tid & 63) * 4;
        *(float4*)(vpml + h2 * 256 + kk) =
            *(const float4*)(vproj + ((size_t)b * 16 + kv * 4 + h2) * 2048 + k0 + kk);
    }
    if (tid < 64) {
        int4 mm = *(const int4*)(mask + b * 2048 + k0 + tid * 4);
        float4 bb;
        bb.x = mm.x ? 0.f : -30000.f;
        bb.y = mm.y ? 0.f : -30000.f;
        bb.z = mm.z ? 0.f : -30000.f;
        bb.w = mm.w ? 0.f : -30000.f;
        *(float4*)(biasl + tid * 4) = bb;
    }
    __syncthreads();

    f32x2 nd[4];
    const f32x2 zero2 = {0.f, 0.f};
    for (int qs = 0; qs < 4; qs++) nd[qs] = zero2;

    for (int t8 = 0; t8 < 16; t8++) {
        const unsigned short* kb = Kl + (t8 * 16 + l15) * 80 + quad * 8;
        bf16x8 a0 = ldfrag(kb);           // A[m=k-row (l15)][k=d 0..31]
        bf16x8 a1 = ldfrag(kb + 32);      // d 32..63
        f32x4 vpm4 = *(const f32x4*)(vpml + w * 256 + t8 * 16 + quad * 4);
        f32x4 c4   = *(const f32x4*)(biasl + t8 * 16 + quad * 4);  // mask bias per k-row
        for (int qs = 0; qs < 4; qs++) {
            __builtin_amdgcn_s_setprio(1);
            f32x4 d = __builtin_amdgcn_mfma_f32_16x16x32_bf16(a0, qf[qs][0], c4, 0, 0, 0);
            d = __builtin_amdgcn_mfma_f32_16x16x32_bf16(a1, qf[qs][1], d, 0, 0, 0);
            __builtin_amdgcn_s_setprio(0);
            for (int r = 0; r < 4; r++) {
                float e = __builtin_amdgcn_exp2f(d[r]);   // 0 for masked rows
                f32x2 m = {vpm4[r], 1.0f};
                nd[qs] += m * e;                          // v_pk_fma_f32: num+=e*v, den+=e
            }
        }
    }
    for (int qs = 0; qs < 4; qs++) {
        float n = nd[qs][0], dd = nd[qs][1];
        n += __shfl_xor(n, 16);  n += __shfl_xor(n, 32);
        dd += __shfl_xor(dd, 16); dd += __shfl_xor(dd, 32);
        if (quad == 0) {
            int q = qrow0 + qs * 16 + l15;
            part[((size_t)(b * 2048 + q) * 16 + h) * 8 + ks] = make_float2(n, dd);
        }
    }
}

// ---------------- combine: out[b,q] = sum_h (sum_ks num)/(sum_ks den)
__global__ __launch_bounds__(256) void combine_kernel(
    const float2* __restrict__ part, float* __restrict__ out)
{
    int wid = (blockIdx.x * 256 + threadIdx.x) >> 6;  // (b,q)
    int lane = threadIdx.x & 63;
    const float2* base = part + (size_t)wid * 128;    // 16 h x 8 ks
    float2 p0 = base[lane];
    float2 p1 = base[64 + lane];
    for (int m = 1; m <= 4; m <<= 1) {
        p0.x += __shfl_xor(p0.x, m); p0.y += __shfl_xor(p0.y, m);
        p1.x += __shfl_xor(p1.x, m); p1.y += __shfl_xor(p1.y, m);
    }
    float v = p0.x / p0.y + p1.x / p1.y;
    for (int m = 8; m <= 32; m <<= 1) v += __shfl_xor(v, m);  // 8 distinct h-groups, once each
    if (lane == 0) out[wid] = v;
}

extern "C" void kernel_launch(void* const* d_in, const int* in_sizes, int n_in,
                              void* d_out, int out_size, void* d_ws, size_t ws_size,
                              hipStream_t stream)
{
    const float* hs  = (const float*)d_in[0];
    const int* mask  = (const int*)d_in[1];
    const float* wq  = (const float*)d_in[2];
    const float* wk  = (const float*)d_in[3];
    const float* wv  = (const float*)d_in[4];
    const float* wo  = (const float*)d_in[5];

    char* ws = (char*)d_ws;
    unsigned short* hs_bf = (unsigned short*)ws;               // 8,388,608 B
    unsigned short* wT    = (unsigned short*)(ws + 8388608);   // 2,883,584 B
    unsigned short* Qp    = (unsigned short*)(ws + 11272192);  // 8,388,608 B
    unsigned short* Kp    = (unsigned short*)(ws + 19660800);  // 2,097,152 B
    float* vproj          = (float*)(ws + 21757952);           //   262,144 B
    float2* part          = (float2*)(ws + 22020096);          // 4,194,304 B

    prep_kernel<<<4928, 256, 0, stream>>>(hs, wq, wk, wv, wo, hs_bf, wT);
    gemm_kernel<<<dim3(11, 32), 256, 0, stream>>>(hs_bf, wT, Qp, Kp, vproj);
    attn_kernel<<<dim3(32, 8, 8), 256, 0, stream>>>(Qp, Kp, vproj, mask, part);
    combine_kernel<<<1024, 256, 0, stream>>>(part, (float*)d_out);
}

// Round 4
// 141.509 us; speedup vs baseline: 1.1132x; 1.0122x over previous
//
#include <hip/hip_runtime.h>
#include <stdint.h>

// CoEncoderDynamicAttention: B=2,S=2048,H=1024,NH=16,NKV=4,HD=64, out=(B,S,1)
// out[b,q] = sum_h (sum_k e_{hqk} * vproj[b,h,k]) / (sum_k e_{hqk})
// vproj = hs @ (wv folded with wo)  -> attn@V GEMM eliminated.
// Q' = hs@wq * (log2e/8)  -> weight = exp2(Q'.K).
// Mask folded as accumulator-init bias (0 / -30000) -> exp2 gives exact 0.
// R1: gemm = double-buffered prefetch pipeline (1 barrier/iter)  [kept]
// R2: attn = R0 structure (2048 blocks, 4 q-chains/wave) + setprio  [kept]
// R3: gemm XCD remap (T1, -6us); attn packed f32x2 accumulate  [kept]
// R4: attn K-tile = linear stride-64 LDS staged via global_load_lds with
//     pre-swizzled source (chunk ^= row&7 at 16B granularity; rule #21),
//     swizzled ds_read_b128 -> conflict-free; LDS 46->37KB = 4 blocks/CU.

typedef __bf16 bf16x8 __attribute__((ext_vector_type(8)));
typedef float f32x4 __attribute__((ext_vector_type(4)));
typedef float f32x2 __attribute__((ext_vector_type(2)));

__device__ inline unsigned short f2bf(float f) {
    unsigned int u = __builtin_bit_cast(unsigned int, f);
    u += 0x7fff + ((u >> 16) & 1);   // RNE
    return (unsigned short)(u >> 16);
}
__device__ inline bf16x8 ldfrag(const unsigned short* p) {
    uint4 v = *(const uint4*)p;
    return __builtin_bit_cast(bf16x8, v);
}
__device__ inline void gl2lds16(const unsigned short* g, unsigned short* l) {
    // 64 lanes x 16B: per-lane global addr, LDS dst = wave-uniform base + lane*16
    __builtin_amdgcn_global_load_lds(
        (const __attribute__((address_space(1))) void*)g,
        (__attribute__((address_space(3))) void*)l, 16, 0, 0);
}

#define SCALE_Q 0.18033688011112042f   // log2(e)/8

// ---------------- prep: hs->bf16; wT = [wq^T*s | wk^T | wvo^T | zeros] (1408x1024 bf16)
__global__ __launch_bounds__(256) void prep_kernel(
    const float* __restrict__ hs, const float* __restrict__ wq,
    const float* __restrict__ wk, const float* __restrict__ wv,
    const float* __restrict__ wo,
    unsigned short* __restrict__ hs_bf, unsigned short* __restrict__ wT)
{
    int bid = blockIdx.x, tid = threadIdx.x;
    if (bid < 4096) {
        int u = bid * 256 + tid;
        float4 v = ((const float4*)hs)[u];
        ushort4 o;
        o.x = f2bf(v.x); o.y = f2bf(v.y); o.z = f2bf(v.z); o.w = f2bf(v.w);
        ((ushort4*)hs_bf)[u] = o;
    } else if (bid < 4416) {
        __shared__ float tile[64 * 65];
        int t = bid - 4096;
        int ntile = t / 16, ctile = t % 16;
        int nb = ntile * 64, cb = ctile * 64;
        int tx = tid & 63, ty = tid >> 6;
        for (int i = 0; i < 16; i++) {
            int cl = i * 4 + ty;
            int n = nb + tx;
            float v = (n < 1024) ? wq[(cb + cl) * 1024 + n] * SCALE_Q
                                 : wk[(cb + cl) * 256 + (n - 1024)];
            tile[cl * 65 + tx] = v;
        }
        __syncthreads();
        for (int i = 0; i < 16; i++) {
            int nl = i * 4 + ty;
            wT[(nb + nl) * 1024 + cb + tx] = f2bf(tile[tx * 65 + nl]);
        }
    } else {
        int u = (bid - 4416) * 256 + tid;
        int n2 = u >> 10, c = u & 1023;
        if (n2 < 16) {
            int h = n2, kv = h >> 2;
            const float* wvr = wv + c * 256 + kv * 64;
            const float* wor = wo + h * 64;
            float s = 0.f;
            #pragma unroll 8
            for (int d = 0; d < 64; d++) s += wvr[d] * wor[d];
            wT[(1280 + n2) * 1024 + c] = f2bf(s);
        } else {
            wT[(1280 + n2) * 1024 + c] = 0;
        }
    }
}

// ---------------- gemm (dbuf pipeline + XCD remap): D[n][r] = sum_c wT[n][c]*hs_bf[r][c]
// n-tiles: 0..7 -> Q' bf16, 8..9 -> K bf16, 10 -> vproj f32
__global__ __launch_bounds__(256) void gemm_kernel(
    const unsigned short* __restrict__ hs_bf, const unsigned short* __restrict__ wT,
    unsigned short* __restrict__ Qp, unsigned short* __restrict__ Kp,
    float* __restrict__ vproj)
{
    __shared__ __align__(16) unsigned short Al[2][128 * 32];  // unpadded: global_load_lds lane order
    __shared__ __align__(16) unsigned short Bl[2][128 * 32];
    // XCD-aware remap: physical flat p -> XCD p%8 (round-robin dispatch).
    // Give XCD x the 4 rt-groups x*4..x*4+3 (44 blocks = 4x11), so the 11
    // same-rt blocks (sharing one 256KB B tile) all sit on one XCD's L2.
    int p = blockIdx.x + 11 * blockIdx.y;   // 0..351
    int xcd = p & 7;
    int j = p >> 3;                          // 0..43
    int rt = (xcd << 2) + j / 11;
    int nt = j % 11;
    int tid = threadIdx.x;
    int lane = tid & 63, w = tid >> 6;
    int l15 = lane & 15, quad = lane >> 4;
    int wm = (w >> 1) * 64, wn = (w & 1) * 64;

    f32x4 acc[4][4];
    const f32x4 zero = {0.f, 0.f, 0.f, 0.f};
    for (int i = 0; i < 4; i++) for (int j2 = 0; j2 < 4; j2++) acc[i][j2] = zero;

    int arow = nt * 128, rrow = rt * 128;
    // staging: wave w covers rows w*32..w*32+31 in two 16-row chunks
    int srow = w * 32 + (lane >> 2);
    int scol = (lane & 3) * 8;
    const unsigned short* ga = wT    + (size_t)(arow + srow) * 1024 + scol;
    const unsigned short* gb = hs_bf + (size_t)(rrow + srow) * 1024 + scol;
    int lofs = (w * 32) * 32;

    // prologue: stage k-tile 0 into buf 0
    gl2lds16(ga,             Al[0] + lofs);
    gl2lds16(ga + 16 * 1024, Al[0] + lofs + 16 * 32);
    gl2lds16(gb,             Bl[0] + lofs);
    gl2lds16(gb + 16 * 1024, Bl[0] + lofs + 16 * 32);
    ga += 32; gb += 32;
    __syncthreads();

    for (int kk = 0; kk < 32; kk++) {
        int cur = kk & 1, nxt = cur ^ 1;
        if (kk < 31) {   // issue next-tile prefetch BEFORE compute; lands by the barrier
            gl2lds16(ga,             Al[nxt] + lofs);
            gl2lds16(ga + 16 * 1024, Al[nxt] + lofs + 16 * 32);
            gl2lds16(gb,             Bl[nxt] + lofs);
            gl2lds16(gb + 16 * 1024, Bl[nxt] + lofs + 16 * 32);
            ga += 32; gb += 32;
        }
        bf16x8 af[4], bfr[4];
        for (int i = 0; i < 4; i++) {
            af[i]  = ldfrag(Al[cur] + (wm + i * 16 + l15) * 32 + quad * 8);
            bfr[i] = ldfrag(Bl[cur] + (wn + i * 16 + l15) * 32 + quad * 8);
        }
        for (int i = 0; i < 4; i++)
            for (int j2 = 0; j2 < 4; j2++)
                acc[i][j2] = __builtin_amdgcn_mfma_f32_16x16x32_bf16(af[i], bfr[j2], acc[i][j2], 0, 0, 0);
        __syncthreads();   // drains prefetch vmcnt + everyone done reading buf[cur]
    }

    for (int i = 0; i < 4; i++) {
        for (int j2 = 0; j2 < 4; j2++) {
            int nw = nt * 128 + wm + i * 16 + quad * 4;
            int r  = rt * 128 + wn + j2 * 16 + l15;
            if (nt < 8) {
                ushort4 o;
                o.x = f2bf(acc[i][j2][0]); o.y = f2bf(acc[i][j2][1]);
                o.z = f2bf(acc[i][j2][2]); o.w = f2bf(acc[i][j2][3]);
                *(ushort4*)(Qp + (size_t)r * 1024 + nw) = o;
            } else if (nt < 10) {
                ushort4 o;
                o.x = f2bf(acc[i][j2][0]); o.y = f2bf(acc[i][j2][1]);
                o.z = f2bf(acc[i][j2][2]); o.w = f2bf(acc[i][j2][3]);
                *(ushort4*)(Kp + (size_t)r * 256 + (nw - 1024)) = o;
            } else {
                for (int rg = 0; rg < 4; rg++) {
                    int h = nw + rg - 1280;
                    if (h < 16)
                        vproj[((size_t)(r >> 11) * 16 + h) * 2048 + (r & 2047)] = acc[i][j2][rg];
                }
            }
        }
    }
}

// ---------------- attention: block = (b,kv,qtile64,ks256); wave w -> h = kv*4+w.
// K tile 256x64 in LINEAR stride-64 LDS, staged via global_load_lds with
// pre-swizzled source: 16B-chunk index ch_stored = ch_data ^ (row&7).
// ds_read_b128 at swizzled chunk -> banks 4*(r&7)%32 spread, 2-way = free.
// LDS 32K(Kl)+4K(vpml)+1K(biasl)=37KB -> 4 blocks/CU (was 3).
// 4 independent q-chains per wave; mask as MFMA C-init bias; setprio (T5);
// packed f32x2 num/den accumulate.
__global__ __launch_bounds__(256) void attn_kernel(
    const unsigned short* __restrict__ Qp, const unsigned short* __restrict__ Kp,
    const float* __restrict__ vproj, const int* __restrict__ mask,
    float2* __restrict__ part)
{
    __shared__ __align__(16) unsigned short Kl[256 * 64];
    __shared__ __align__(16) float vpml[4 * 256];
    __shared__ __align__(16) float biasl[256];
    int qt = blockIdx.x;                       // 0..31
    int b = blockIdx.y >> 2, kv = blockIdx.y & 3;
    int ks = blockIdx.z;                       // 0..7
    int tid = threadIdx.x, lane = tid & 63, w = tid >> 6;
    int l15 = lane & 15, quad = lane >> 4;
    int h = kv * 4 + w;
    int k0 = ks * 256;
    int qrow0 = qt * 64;

    // Q fragments: B-operand layout B[n=q (l15)][k=d (quad*8..)]
    bf16x8 qf[4][2];
    for (int qs = 0; qs < 4; qs++) {
        const unsigned short* qp =
            Qp + (size_t)(b * 2048 + qrow0 + qs * 16 + l15) * 1024 + h * 64 + quad * 8;
        qf[qs][0] = ldfrag(qp);
        qf[qs][1] = ldfrag(qp + 32);
    }

    // stage K (256 rows x 64 d) via gl2lds16, 64 rows per wave, 8 rows per call.
    // LDS linear: row r at Kl + r*64, lane's 16B lands at chunk (lane&7).
    // Source pre-swizzle: fetch data-chunk (lane&7)^(r&7); r&7 == (lane>>3)&7.
    {
        int swz = (lane & 7) ^ ((lane >> 3) & 7);          // lane-pure
        const unsigned short* kbase =
            Kp + (size_t)(b * 2048 + k0 + w * 64 + (lane >> 3)) * 256 + kv * 64 + swz * 8;
        unsigned short* ldst = Kl + (w * 64) * 64;
        #pragma unroll
        for (int j = 0; j < 8; j++)
            gl2lds16(kbase + (size_t)(j * 8) * 256, ldst + j * 8 * 64);
    }
    {   // vproj slice per h (4 h x 256 k)
        int h2 = tid >> 6, kk = (tid & 63) * 4;
        *(float4*)(vpml + h2 * 256 + kk) =
            *(const float4*)(vproj + ((size_t)b * 16 + kv * 4 + h2) * 2048 + k0 + kk);
    }
    if (tid < 64) {
        int4 mm = *(const int4*)(mask + b * 2048 + k0 + tid * 4);
        float4 bb;
        bb.x = mm.x ? 0.f : -30000.f;
        bb.y = mm.y ? 0.f : -30000.f;
        bb.z = mm.z ? 0.f : -30000.f;
        bb.w = mm.w ? 0.f : -30000.f;
        *(float4*)(biasl + tid * 4) = bb;
    }
    __syncthreads();

    f32x2 nd[4];
    const f32x2 zero2 = {0.f, 0.f};
    for (int qs = 0; qs < 4; qs++) nd[qs] = zero2;

    for (int t8 = 0; t8 < 16; t8++) {
        int r0 = t8 * 16 + l15;
        int rx = r0 & 7;
        // data-chunk quad (d 0..31) stored at chunk quad^rx; d 32..63 at (quad^4)^rx
        bf16x8 a0 = ldfrag(Kl + r0 * 64 + ((quad ^ rx) * 8));
        bf16x8 a1 = ldfrag(Kl + r0 * 64 + (((quad ^ rx) ^ 4) * 8));
        f32x4 vpm4 = *(const f32x4*)(vpml + w * 256 + t8 * 16 + quad * 4);
        f32x4 c4   = *(const f32x4*)(biasl + t8 * 16 + quad * 4);  // mask bias per k-row
        for (int qs = 0; qs < 4; qs++) {
            __builtin_amdgcn_s_setprio(1);
            f32x4 d = __builtin_amdgcn_mfma_f32_16x16x32_bf16(a0, qf[qs][0], c4, 0, 0, 0);
            d = __builtin_amdgcn_mfma_f32_16x16x32_bf16(a1, qf[qs][1], d, 0, 0, 0);
            __builtin_amdgcn_s_setprio(0);
            for (int r = 0; r < 4; r++) {
                float e = __builtin_amdgcn_exp2f(d[r]);   // 0 for masked rows
                f32x2 m = {vpm4[r], 1.0f};
                nd[qs] += m * e;                          // v_pk_fma_f32: num+=e*v, den+=e
            }
        }
    }
    for (int qs = 0; qs < 4; qs++) {
        float n = nd[qs][0], dd = nd[qs][1];
        n += __shfl_xor(n, 16);  n += __shfl_xor(n, 32);
        dd += __shfl_xor(dd, 16); dd += __shfl_xor(dd, 32);
        if (quad == 0) {
            int q = qrow0 + qs * 16 + l15;
            part[((size_t)(b * 2048 + q) * 16 + h) * 8 + ks] = make_float2(n, dd);
        }
    }
}

// ---------------- combine: out[b,q] = sum_h (sum_ks num)/(sum_ks den)
__global__ __launch_bounds__(256) void combine_kernel(
    const float2* __restrict__ part, float* __restrict__ out)
{
    int wid = (blockIdx.x * 256 + threadIdx.x) >> 6;  // (b,q)
    int lane = threadIdx.x & 63;
    const float2* base = part + (size_t)wid * 128;    // 16 h x 8 ks
    float2 p0 = base[lane];
    float2 p1 = base[64 + lane];
    for (int m = 1; m <= 4; m <<= 1) {
        p0.x += __shfl_xor(p0.x, m); p0.y += __shfl_xor(p0.y, m);
        p1.x += __shfl_xor(p1.x, m); p1.y += __shfl_xor(p1.y, m);
    }
    float v = p0.x / p0.y + p1.x / p1.y;
    for (int m = 8; m <= 32; m <<= 1) v += __shfl_xor(v, m);  // 8 distinct h-groups, once each
    if (lane == 0) out[wid] = v;
}

extern "C" void kernel_launch(void* const* d_in, const int* in_sizes, int n_in,
                              void* d_out, int out_size, void* d_ws, size_t ws_size,
                              hipStream_t stream)
{
    const float* hs  = (const float*)d_in[0];
    const int* mask  = (const int*)d_in[1];
    const float* wq  = (const float*)d_in[2];
    const float* wk  = (const float*)d_in[3];
    const float* wv  = (const float*)d_in[4];
    const float* wo  = (const float*)d_in[5];

    char* ws = (char*)d_ws;
    unsigned short* hs_bf = (unsigned short*)ws;               // 8,388,608 B
    unsigned short* wT    = (unsigned short*)(ws + 8388608);   // 2,883,584 B
    unsigned short* Qp    = (unsigned short*)(ws + 11272192);  // 8,388,608 B
    unsigned short* Kp    = (unsigned short*)(ws + 19660800);  // 2,097,152 B
    float* vproj          = (float*)(ws + 21757952);           //   262,144 B
    float2* part          = (float2*)(ws + 22020096);          // 4,194,304 B

    prep_kernel<<<4928, 256, 0, stream>>>(hs, wq, wk, wv, wo, hs_bf, wT);
    gemm_kernel<<<dim3(11, 32), 256, 0, stream>>>(hs_bf, wT, Qp, Kp, vproj);
    attn_kernel<<<dim3(32, 8, 8), 256, 0, stream>>>(Qp, Kp, vproj, mask, part);
    combine_kernel<<<1024, 256, 0, stream>>>(part, (float*)d_out);
}

// Round 5
// 140.048 us; speedup vs baseline: 1.1248x; 1.0104x over previous
//
#include <hip/hip_runtime.h>
#include <stdint.h>

// CoEncoderDynamicAttention: B=2,S=2048,H=1024,NH=16,NKV=4,HD=64, out=(B,S,1)
// out[b,q] = sum_h (sum_k e_{hqk} * vproj[b,h,k]) / (sum_k e_{hqk})
// vproj = hs @ (wv folded with wo)  -> attn@V GEMM eliminated.
// Q' = hs@wq * (log2e/8)  -> weight = exp2(Q'.K).
// Mask folded as accumulator-init bias (0 / -30000) -> exp2 gives exact 0.
// R1: gemm dbuf prefetch pipeline (1 barrier/iter)  [kept]
// R2: attn R0 structure (2048 blocks, 4 q-chains/wave) + setprio  [kept]
// R3: gemm XCD remap (T1, -6us); attn packed f32x2 accumulate  [kept]
// R4: attn K-tile via global_load_lds + XOR-swizzled source; 37KB LDS  [kept]
// R5: gemm r-tile 128->64: grid (11,64)=704 blocks=2.75/CU (was 1.375 ->
//     barrier drains had no second block to hide under); remap 88/XCD =
//     8 rt x 11 nt. attn: K-DMA issued before Q loads.

typedef __bf16 bf16x8 __attribute__((ext_vector_type(8)));
typedef float f32x4 __attribute__((ext_vector_type(4)));
typedef float f32x2 __attribute__((ext_vector_type(2)));

__device__ inline unsigned short f2bf(float f) {
    unsigned int u = __builtin_bit_cast(unsigned int, f);
    u += 0x7fff + ((u >> 16) & 1);   // RNE
    return (unsigned short)(u >> 16);
}
__device__ inline bf16x8 ldfrag(const unsigned short* p) {
    uint4 v = *(const uint4*)p;
    return __builtin_bit_cast(bf16x8, v);
}
__device__ inline void gl2lds16(const unsigned short* g, unsigned short* l) {
    // 64 lanes x 16B: per-lane global addr, LDS dst = wave-uniform base + lane*16
    __builtin_amdgcn_global_load_lds(
        (const __attribute__((address_space(1))) void*)g,
        (__attribute__((address_space(3))) void*)l, 16, 0, 0);
}

#define SCALE_Q 0.18033688011112042f   // log2(e)/8

// ---------------- prep: hs->bf16; wT = [wq^T*s | wk^T | wvo^T | zeros] (1408x1024 bf16)
__global__ __launch_bounds__(256) void prep_kernel(
    const float* __restrict__ hs, const float* __restrict__ wq,
    const float* __restrict__ wk, const float* __restrict__ wv,
    const float* __restrict__ wo,
    unsigned short* __restrict__ hs_bf, unsigned short* __restrict__ wT)
{
    int bid = blockIdx.x, tid = threadIdx.x;
    if (bid < 4096) {
        int u = bid * 256 + tid;
        float4 v = ((const float4*)hs)[u];
        ushort4 o;
        o.x = f2bf(v.x); o.y = f2bf(v.y); o.z = f2bf(v.z); o.w = f2bf(v.w);
        ((ushort4*)hs_bf)[u] = o;
    } else if (bid < 4416) {
        __shared__ float tile[64 * 65];
        int t = bid - 4096;
        int ntile = t / 16, ctile = t % 16;
        int nb = ntile * 64, cb = ctile * 64;
        int tx = tid & 63, ty = tid >> 6;
        for (int i = 0; i < 16; i++) {
            int cl = i * 4 + ty;
            int n = nb + tx;
            float v = (n < 1024) ? wq[(cb + cl) * 1024 + n] * SCALE_Q
                                 : wk[(cb + cl) * 256 + (n - 1024)];
            tile[cl * 65 + tx] = v;
        }
        __syncthreads();
        for (int i = 0; i < 16; i++) {
            int nl = i * 4 + ty;
            wT[(nb + nl) * 1024 + cb + tx] = f2bf(tile[tx * 65 + nl]);
        }
    } else {
        int u = (bid - 4416) * 256 + tid;
        int n2 = u >> 10, c = u & 1023;
        if (n2 < 16) {
            int h = n2, kv = h >> 2;
            const float* wvr = wv + c * 256 + kv * 64;
            const float* wor = wo + h * 64;
            float s = 0.f;
            #pragma unroll 8
            for (int d = 0; d < 64; d++) s += wvr[d] * wor[d];
            wT[(1280 + n2) * 1024 + c] = f2bf(s);
        } else {
            wT[(1280 + n2) * 1024 + c] = 0;
        }
    }
}

// ---------------- gemm (dbuf + XCD remap, 128n x 64r tiles): D[n][r] = sum_c wT[n][c]*hs_bf[r][c]
// n-tiles: 0..7 -> Q' bf16, 8..9 -> K bf16, 10 -> vproj f32
__global__ __launch_bounds__(256) void gemm_kernel(
    const unsigned short* __restrict__ hs_bf, const unsigned short* __restrict__ wT,
    unsigned short* __restrict__ Qp, unsigned short* __restrict__ Kp,
    float* __restrict__ vproj)
{
    __shared__ __align__(16) unsigned short Al[2][128 * 32];  // unpadded: global_load_lds lane order
    __shared__ __align__(16) unsigned short Bl[2][64 * 32];
    // XCD-aware remap: physical flat p -> XCD p%8 (round-robin dispatch).
    // XCD x gets rt-groups x*8..x*8+7 (88 blocks = 8x11): the 11 same-rt
    // blocks (sharing one 128KB B tile) all sit on one XCD's L2.
    int p = blockIdx.x + 11 * blockIdx.y;   // 0..703
    int xcd = p & 7;
    int j = p >> 3;                          // 0..87
    int rt = (xcd << 3) + j / 11;            // 0..63
    int nt = j % 11;
    int tid = threadIdx.x;
    int lane = tid & 63, w = tid >> 6;
    int l15 = lane & 15, quad = lane >> 4;
    int wm = (w >> 1) * 64, wn = (w & 1) * 32;

    f32x4 acc[4][2];
    const f32x4 zero = {0.f, 0.f, 0.f, 0.f};
    for (int i = 0; i < 4; i++) for (int j2 = 0; j2 < 2; j2++) acc[i][j2] = zero;

    int arow = nt * 128, rrow = rt * 64;
    // A staging: wave w rows w*32..w*32+31 (two 16-row chunks)
    // B staging: wave w rows w*16..w*16+15 (one chunk)
    int srowA = w * 32 + (lane >> 2);
    int srowB = w * 16 + (lane >> 2);
    int scol = (lane & 3) * 8;
    const unsigned short* ga = wT    + (size_t)(arow + srowA) * 1024 + scol;
    const unsigned short* gb = hs_bf + (size_t)(rrow + srowB) * 1024 + scol;
    int lofsA = (w * 32) * 32;
    int lofsB = (w * 16) * 32;

    // prologue: stage k-tile 0 into buf 0
    gl2lds16(ga,             Al[0] + lofsA);
    gl2lds16(ga + 16 * 1024, Al[0] + lofsA + 16 * 32);
    gl2lds16(gb,             Bl[0] + lofsB);
    ga += 32; gb += 32;
    __syncthreads();

    for (int kk = 0; kk < 32; kk++) {
        int cur = kk & 1, nxt = cur ^ 1;
        if (kk < 31) {   // issue next-tile prefetch BEFORE compute; lands by the barrier
            gl2lds16(ga,             Al[nxt] + lofsA);
            gl2lds16(ga + 16 * 1024, Al[nxt] + lofsA + 16 * 32);
            gl2lds16(gb,             Bl[nxt] + lofsB);
            ga += 32; gb += 32;
        }
        bf16x8 af[4], bfr[2];
        for (int i = 0; i < 4; i++)
            af[i]  = ldfrag(Al[cur] + (wm + i * 16 + l15) * 32 + quad * 8);
        for (int j2 = 0; j2 < 2; j2++)
            bfr[j2] = ldfrag(Bl[cur] + (wn + j2 * 16 + l15) * 32 + quad * 8);
        for (int i = 0; i < 4; i++)
            for (int j2 = 0; j2 < 2; j2++)
                acc[i][j2] = __builtin_amdgcn_mfma_f32_16x16x32_bf16(af[i], bfr[j2], acc[i][j2], 0, 0, 0);
        __syncthreads();   // drains prefetch vmcnt + everyone done reading buf[cur]
    }

    for (int i = 0; i < 4; i++) {
        for (int j2 = 0; j2 < 2; j2++) {
            int nw = nt * 128 + wm + i * 16 + quad * 4;
            int r  = rt * 64 + wn + j2 * 16 + l15;
            if (nt < 8) {
                ushort4 o;
                o.x = f2bf(acc[i][j2][0]); o.y = f2bf(acc[i][j2][1]);
                o.z = f2bf(acc[i][j2][2]); o.w = f2bf(acc[i][j2][3]);
                *(ushort4*)(Qp + (size_t)r * 1024 + nw) = o;
            } else if (nt < 10) {
                ushort4 o;
                o.x = f2bf(acc[i][j2][0]); o.y = f2bf(acc[i][j2][1]);
                o.z = f2bf(acc[i][j2][2]); o.w = f2bf(acc[i][j2][3]);
                *(ushort4*)(Kp + (size_t)r * 256 + (nw - 1024)) = o;
            } else {
                for (int rg = 0; rg < 4; rg++) {
                    int h = nw + rg - 1280;
                    if (h < 16)
                        vproj[((size_t)(r >> 11) * 16 + h) * 2048 + (r & 2047)] = acc[i][j2][rg];
                }
            }
        }
    }
}

// ---------------- attention: block = (b,kv,qtile64,ks256); wave w -> h = kv*4+w.
// K tile 256x64 in LINEAR stride-64 LDS, staged via global_load_lds with
// pre-swizzled source (chunk ^= row&7 at 16B granularity); conflict-free reads.
// K-DMA issued first so its latency hides under Q-fragment loads.
// 4 independent q-chains per wave; mask as MFMA C-init bias; setprio (T5);
// packed f32x2 num/den accumulate. LDS 37KB -> 4 blocks/CU.
__global__ __launch_bounds__(256) void attn_kernel(
    const unsigned short* __restrict__ Qp, const unsigned short* __restrict__ Kp,
    const float* __restrict__ vproj, const int* __restrict__ mask,
    float2* __restrict__ part)
{
    __shared__ __align__(16) unsigned short Kl[256 * 64];
    __shared__ __align__(16) float vpml[4 * 256];
    __shared__ __align__(16) float biasl[256];
    int qt = blockIdx.x;                       // 0..31
    int b = blockIdx.y >> 2, kv = blockIdx.y & 3;
    int ks = blockIdx.z;                       // 0..7
    int tid = threadIdx.x, lane = tid & 63, w = tid >> 6;
    int l15 = lane & 15, quad = lane >> 4;
    int h = kv * 4 + w;
    int k0 = ks * 256;
    int qrow0 = qt * 64;

    // stage K FIRST (fire-and-forget DMA; latency hides under Q loads below).
    // LDS linear: row r at Kl + r*64, lane's 16B at chunk (lane&7).
    // Source pre-swizzle: fetch data-chunk (lane&7)^(r&7); r&7 == (lane>>3)&7.
    {
        int swz = (lane & 7) ^ ((lane >> 3) & 7);          // lane-pure
        const unsigned short* kbase =
            Kp + (size_t)(b * 2048 + k0 + w * 64 + (lane >> 3)) * 256 + kv * 64 + swz * 8;
        unsigned short* ldst = Kl + (w * 64) * 64;
        #pragma unroll
        for (int j = 0; j < 8; j++)
            gl2lds16(kbase + (size_t)(j * 8) * 256, ldst + j * 8 * 64);
    }

    // Q fragments: B-operand layout B[n=q (l15)][k=d (quad*8..)]
    bf16x8 qf[4][2];
    for (int qs = 0; qs < 4; qs++) {
        const unsigned short* qp =
            Qp + (size_t)(b * 2048 + qrow0 + qs * 16 + l15) * 1024 + h * 64 + quad * 8;
        qf[qs][0] = ldfrag(qp);
        qf[qs][1] = ldfrag(qp + 32);
    }

    {   // vproj slice per h (4 h x 256 k)
        int h2 = tid >> 6, kk = (tid & 63) * 4;
        *(float4*)(vpml + h2 * 256 + kk) =
            *(const float4*)(vproj + ((size_t)b * 16 + kv * 4 + h2) * 2048 + k0 + kk);
    }
    if (tid < 64) {
        int4 mm = *(const int4*)(mask + b * 2048 + k0 + tid * 4);
        float4 bb;
        bb.x = mm.x ? 0.f : -30000.f;
        bb.y = mm.y ? 0.f : -30000.f;
        bb.z = mm.z ? 0.f : -30000.f;
        bb.w = mm.w ? 0.f : -30000.f;
        *(float4*)(biasl + tid * 4) = bb;
    }
    __syncthreads();

    f32x2 nd[4];
    const f32x2 zero2 = {0.f, 0.f};
    for (int qs = 0; qs < 4; qs++) nd[qs] = zero2;

    for (int t8 = 0; t8 < 16; t8++) {
        int r0 = t8 * 16 + l15;
        int rx = r0 & 7;
        // data-chunk quad (d 0..31) stored at chunk quad^rx; d 32..63 at (quad^4)^rx
        bf16x8 a0 = ldfrag(Kl + r0 * 64 + ((quad ^ rx) * 8));
        bf16x8 a1 = ldfrag(Kl + r0 * 64 + (((quad ^ rx) ^ 4) * 8));
        f32x4 vpm4 = *(const f32x4*)(vpml + w * 256 + t8 * 16 + quad * 4);
        f32x4 c4   = *(const f32x4*)(biasl + t8 * 16 + quad * 4);  // mask bias per k-row
        for (int qs = 0; qs < 4; qs++) {
            __builtin_amdgcn_s_setprio(1);
            f32x4 d = __builtin_amdgcn_mfma_f32_16x16x32_bf16(a0, qf[qs][0], c4, 0, 0, 0);
            d = __builtin_amdgcn_mfma_f32_16x16x32_bf16(a1, qf[qs][1], d, 0, 0, 0);
            __builtin_amdgcn_s_setprio(0);
            for (int r = 0; r < 4; r++) {
                float e = __builtin_amdgcn_exp2f(d[r]);   // 0 for masked rows
                f32x2 m = {vpm4[r], 1.0f};
                nd[qs] += m * e;                          // v_pk_fma_f32: num+=e*v, den+=e
            }
        }
    }
    for (int qs = 0; qs < 4; qs++) {
        float n = nd[qs][0], dd = nd[qs][1];
        n += __shfl_xor(n, 16);  n += __shfl_xor(n, 32);
        dd += __shfl_xor(dd, 16); dd += __shfl_xor(dd, 32);
        if (quad == 0) {
            int q = qrow0 + qs * 16 + l15;
            part[((size_t)(b * 2048 + q) * 16 + h) * 8 + ks] = make_float2(n, dd);
        }
    }
}

// ---------------- combine: out[b,q] = sum_h (sum_ks num)/(sum_ks den)
__global__ __launch_bounds__(256) void combine_kernel(
    const float2* __restrict__ part, float* __restrict__ out)
{
    int wid = (blockIdx.x * 256 + threadIdx.x) >> 6;  // (b,q)
    int lane = threadIdx.x & 63;
    const float2* base = part + (size_t)wid * 128;    // 16 h x 8 ks
    float2 p0 = base[lane];
    float2 p1 = base[64 + lane];
    for (int m = 1; m <= 4; m <<= 1) {
        p0.x += __shfl_xor(p0.x, m); p0.y += __shfl_xor(p0.y, m);
        p1.x += __shfl_xor(p1.x, m); p1.y += __shfl_xor(p1.y, m);
    }
    float v = p0.x / p0.y + p1.x / p1.y;
    for (int m = 8; m <= 32; m <<= 1) v += __shfl_xor(v, m);  // 8 distinct h-groups, once each
    if (lane == 0) out[wid] = v;
}

extern "C" void kernel_launch(void* const* d_in, const int* in_sizes, int n_in,
                              void* d_out, int out_size, void* d_ws, size_t ws_size,
                              hipStream_t stream)
{
    const float* hs  = (const float*)d_in[0];
    const int* mask  = (const int*)d_in[1];
    const float* wq  = (const float*)d_in[2];
    const float* wk  = (const float*)d_in[3];
    const float* wv  = (const float*)d_in[4];
    const float* wo  = (const float*)d_in[5];

    char* ws = (char*)d_ws;
    unsigned short* hs_bf = (unsigned short*)ws;               // 8,388,608 B
    unsigned short* wT    = (unsigned short*)(ws + 8388608);   // 2,883,584 B
    unsigned short* Qp    = (unsigned short*)(ws + 11272192);  // 8,388,608 B
    unsigned short* Kp    = (unsigned short*)(ws + 19660800);  // 2,097,152 B
    float* vproj          = (float*)(ws + 21757952);           //   262,144 B
    float2* part          = (float2*)(ws + 22020096);          // 4,194,304 B

    prep_kernel<<<4928, 256, 0, stream>>>(hs, wq, wk, wv, wo, hs_bf, wT);
    gemm_kernel<<<dim3(11, 64), 256, 0, stream>>>(hs_bf, wT, Qp, Kp, vproj);
    attn_kernel<<<dim3(32, 8, 8), 256, 0, stream>>>(Qp, Kp, vproj, mask, part);
    combine_kernel<<<1024, 256, 0, stream>>>(part, (float*)d_out);
}